// Round 16
// baseline (269.711 us; speedup 1.0000x reference)
//
#include <hip/hip_runtime.h>

typedef __attribute__((ext_vector_type(8))) short bf8;
typedef __attribute__((ext_vector_type(4))) float f4;
typedef __attribute__((ext_vector_type(16))) float f16v;
typedef __attribute__((ext_vector_type(2))) unsigned int u32x2;
typedef __attribute__((ext_vector_type(4))) unsigned int u32x4;

#define MFMA16(A,B,C) __builtin_amdgcn_mfma_f32_16x16x32_bf16(A,B,C,0,0,0)
#define MFMA32(A,B,C) __builtin_amdgcn_mfma_f32_32x32x16_bf16(A,B,C,0,0,0)

#define NTOK 98
#define SROW 136
#define LOG2E 1.4426950408889634f
#define QSCALE (0.17677669529663687f * LOG2E)   // head scale * log2(e)

__device__ __forceinline__ unsigned short bfu(float f) {
  union { float f; unsigned u; } un; un.f = f;
  unsigned r = un.u + 0x7FFFu + ((un.u >> 16) & 1u);
  return (unsigned short)(r >> 16);
}
__device__ __forceinline__ unsigned cvtpk(float a, float b) {
  unsigned r;
  asm("v_cvt_pk_bf16_f32 %0, %1, %2" : "=v"(r) : "v"(a), "v"(b));
  return r;
}
__device__ __forceinline__ float h2f(unsigned short u) {
  return (float)__builtin_bit_cast(_Float16, u);
}

__global__ void prep_kernel(const float* __restrict__ qkv_w,
                            const float* __restrict__ proj_w,
                            const float* __restrict__ bias_table,
                            const int* __restrict__ rel_index,
                            const float* __restrict__ mask,
                            unsigned short* __restrict__ wq,
                            unsigned short* __restrict__ wp,
                            float* __restrict__ bsmall,
                            unsigned short* __restrict__ bmh, int use_bm) {
  const int T1 = 384*128, T2 = T1 + 128*128;
  const int TS = 4*128*112;
  const int T3 = T2 + TS;
  const int TB = 64*4*128*112;
  const int total = T3 + (use_bm ? TB : 0);
  for (int idx = blockIdx.x*blockDim.x + threadIdx.x; idx < total;
       idx += gridDim.x*blockDim.x) {
    if (idx < T1)      wq[idx] = bfu(qkv_w[idx]);
    else if (idx < T2) wp[idx - T1] = bfu(proj_w[idx - T1]);
    else if (idx < T3) {
      int t = idx - T2;
      int m = t % 112, n = (t/112) & 127, h = t / (112*128);
      float v;
      if (m >= NTOK)      v = -1e30f;
      else if (n >= NTOK) v = 0.f;
      else                v = bias_table[rel_index[n*98+m]*4 + h] * LOG2E;
      bsmall[t] = v;
    } else {
      int t = idx - T3;
      int m = t % 112; int r = t / 112;
      int n = r & 127; r >>= 7;
      int h = r & 3;   int w = r >> 2;
      float v;
      if (m >= NTOK)      v = -1e30f;   // fp16 -inf -> exp2 = 0
      else if (n >= NTOK) v = 0.f;
      else v = (bias_table[rel_index[n*98+m]*4 + h] + mask[(size_t)w*9604 + n*98 + m]) * LOG2E;
      bmh[t] = __builtin_bit_cast(unsigned short, (_Float16)v);
    }
  }
}

template<int USE_BM>
__launch_bounds__(1024, 1)
__global__ void wattn_kernel(const float* __restrict__ x,
                             const float* __restrict__ mask,
                             const float* __restrict__ proj_b,
                             const unsigned short* __restrict__ wqkv,
                             const unsigned short* __restrict__ wproj,
                             const float* __restrict__ bsmall,
                             const unsigned short* __restrict__ bmh,
                             float* __restrict__ out) {
  __shared__ unsigned short xb[128*SROW];   // x bf16, reused as attn-out [n][d]
  __shared__ unsigned short qb[128*SROW];   // q (QSCALE'd) [n][d]
  __shared__ unsigned short kb[128*SROW];   // k [m][d]
  __shared__ unsigned short vt[128*SROW];   // V^T [d][token]

  const int b = blockIdx.x, tid = threadIdx.x;
  const int wid = tid >> 6, lane = tid & 63;
  const int g = lane >> 4, c = lane & 15;
  const int hh = wid & 3, i32 = wid >> 2;
  const int l31 = lane & 31, hl = lane >> 5;
  const int nA = i32*32 + l31;

  // proj prefetch registers (loaded mid-attention, consumed after the barrier)
  bf8 pjw[4];
  f4  pjb;

  // ---- issue x loads early ----
  const float4* xp4 = (const float4*)(x + (size_t)b * (NTOK*128));
  float4 xv0 = xp4[tid];
  float4 xv1 = xp4[tid + 1024];
  float4 xv2 = xp4[tid + 2048];
  float4 xv3;
  const bool has3 = tid < 64;               // 3136 total float4
  if (has3) xv3 = xp4[tid + 3072];

  // zero pads: xb rows 98..111, qb/kb rows 112..127
  for (int i = tid; i < 14*SROW; i += 1024) xb[98*SROW + i] = 0;
  for (int i = tid; i < 16*SROW; i += 1024) { qb[112*SROW + i] = 0; kb[112*SROW + i] = 0; }

  // ---- convert + stage x ----
  {
    int e = tid*4, nn = e >> 7, cc = e & 127;
    u32x2 u; u[0] = cvtpk(xv0.x, xv0.y); u[1] = cvtpk(xv0.z, xv0.w);
    *(u32x2*)&xb[nn*SROW + cc] = u;
    e = (tid+1024)*4; nn = e >> 7; cc = e & 127;
    u[0] = cvtpk(xv1.x, xv1.y); u[1] = cvtpk(xv1.z, xv1.w);
    *(u32x2*)&xb[nn*SROW + cc] = u;
    e = (tid+2048)*4; nn = e >> 7; cc = e & 127;
    u[0] = cvtpk(xv2.x, xv2.y); u[1] = cvtpk(xv2.z, xv2.w);
    *(u32x2*)&xb[nn*SROW + cc] = u;
    if (has3) {
      e = (tid+3072)*4; nn = e >> 7; cc = e & 127;
      u[0] = cvtpk(xv3.x, xv3.y); u[1] = cvtpk(xv3.z, xv3.w);
      *(u32x2*)&xb[nn*SROW + cc] = u;
    }
  }
  __syncthreads();

  // ---- QKV: fused q/k/v for tile t = wid>>1, half = wid&1.
  // Identical math to R3's three tasks (q/k swapped, v unswapped) but each xf
  // LDS fragment is loaded ONCE and shared (48 -> 16 ds_read_b128 per wave).
  {
    const int t = wid >> 1, half = wid & 1;
    const int ib = half ? 4 : 0, ni = half ? 3 : 4;
    const unsigned short* wq_p = wqkv + (size_t)(t*16 + c)*128;         // q rows
    const unsigned short* wk_p = wqkv + (size_t)(128 + t*16 + c)*128;   // k rows
    const unsigned short* wv_p = wqkv + (size_t)(256 + t*16 + c)*128;   // v rows
    f4 aq[4] = {}, ak[4] = {}, av[4] = {};
    #pragma unroll
    for (int kk = 0; kk < 4; ++kk) {
      bf8 wqf = *(const bf8*)(wq_p + kk*32 + g*8);
      bf8 wkf = *(const bf8*)(wk_p + kk*32 + g*8);
      bf8 wvf = *(const bf8*)(wv_p + kk*32 + g*8);
      #pragma unroll
      for (int i = 0; i < 4; ++i) if (i < ni) {
        bf8 xf = *(const bf8*)(&xb[((ib+i)*16 + c)*SROW + kk*32 + g*8]);
        aq[i] = MFMA16(wqf, xf, aq[i]);   // D[o'][n'] -> q^T tile
        ak[i] = MFMA16(wkf, xf, ak[i]);   // D[o'][n'] -> k^T tile
        av[i] = MFMA16(xf, wvf, av[i]);   // D[n'][o'] -> V^T tile
      }
    }
    const int col = t*16 + g*4;
    #pragma unroll
    for (int i = 0; i < 4; ++i) if (i < ni) {
      u32x2 uu;
      uu[0] = cvtpk(aq[i][0]*QSCALE, aq[i][1]*QSCALE);
      uu[1] = cvtpk(aq[i][2]*QSCALE, aq[i][3]*QSCALE);
      *(u32x2*)&qb[((ib+i)*16 + c)*SROW + col] = uu;
      uu[0] = cvtpk(ak[i][0], ak[i][1]);
      uu[1] = cvtpk(ak[i][2], ak[i][3]);
      *(u32x2*)&kb[((ib+i)*16 + c)*SROW + col] = uu;
      uu[0] = cvtpk(av[i][0], av[i][1]);
      uu[1] = cvtpk(av[i][2], av[i][3]);
      *(u32x2*)&vt[(t*16 + c)*SROW + (ib+i)*16 + g*4] = uu;
    }
  }
  __syncthreads();

  // ---- attention: 1 task/wave; fp16 bm as MFMA C-init (loads at phase entry) ----
  {
    f16v sj[4];
    if (USE_BM) {
      const unsigned short* bp = bmh + ((size_t)((b & 63)*4 + hh)*128 + nA)*112;
      #pragma unroll
      for (int j = 0; j < 4; ++j)
        #pragma unroll
        for (int a = 0; a < 4; ++a) {
          if (j == 3 && a >= 2) {
            sj[j][4*a+0] = 0.f; sj[j][4*a+1] = 0.f;
            sj[j][4*a+2] = 0.f; sj[j][4*a+3] = 0.f;   // masked region: P=0 directly
          } else {
            ushort4 t = *(const ushort4*)(bp + j*32 + a*8 + hl*4);
            sj[j][4*a+0] = h2f(t.x); sj[j][4*a+1] = h2f(t.y);
            sj[j][4*a+2] = h2f(t.z); sj[j][4*a+3] = h2f(t.w);
          }
        }
    } else {
      const float* bs = bsmall + ((size_t)hh*128 + nA)*112;
      #pragma unroll
      for (int j = 0; j < 4; ++j)
        #pragma unroll
        for (int a = 0; a < 4; ++a) {
          if (j == 3 && a >= 2) {
            sj[j][4*a+0] = 0.f; sj[j][4*a+1] = 0.f;
            sj[j][4*a+2] = 0.f; sj[j][4*a+3] = 0.f;
          } else {
            f4 t = *(const f4*)(bs + j*32 + a*8 + hl*4);
            sj[j][4*a+0] = t[0]; sj[j][4*a+1] = t[1];
            sj[j][4*a+2] = t[2]; sj[j][4*a+3] = t[3];
          }
        }
    }
    if (!USE_BM && nA < NTOK) {
      const float* mw = mask + (size_t)(b & 63)*9604 + (size_t)nA*98;
      #pragma unroll
      for (int j = 0; j < 4; ++j)
        #pragma unroll
        for (int a = 0; a < 4; ++a) {
          if (j == 3 && a >= 2) continue;
          #pragma unroll
          for (int bb = 0; bb < 4; ++bb) {
            int m = j*32 + a*8 + hl*4 + bb;
            if (m < NTOK) sj[j][4*a+bb] += mw[m] * LOG2E;
          }
        }
    }
    // QK^T: S^T[m][n], col n = nA
    #pragma unroll
    for (int kd = 0; kd < 2; ++kd) {
      bf8 qf = *(const bf8*)&qb[nA*SROW + hh*32 + kd*16 + hl*8];
      #pragma unroll
      for (int j = 0; j < 4; ++j) {
        bf8 kf = *(const bf8*)&kb[(j*32 + l31)*SROW + hh*32 + kd*16 + hl*8];
        sj[j] = MFMA32(kf, qf, sj[j]);
      }
    }
    // softmax: exp2 (log2e pre-folded); skip 8 always-masked regs
    float sum = 0.f;
    #pragma unroll
    for (int j = 0; j < 4; ++j)
      #pragma unroll
      for (int a = 0; a < 4; ++a) {
        if (j == 3 && a >= 2) {
          sj[j][4*a+0] = 0.f; sj[j][4*a+1] = 0.f;
          sj[j][4*a+2] = 0.f; sj[j][4*a+3] = 0.f;
          continue;
        }
        float e0 = exp2f(sj[j][4*a+0]);
        float e1 = exp2f(sj[j][4*a+1]);
        float e2 = exp2f(sj[j][4*a+2]);
        float e3 = exp2f(sj[j][4*a+3]);
        sj[j][4*a+0] = e0; sj[j][4*a+1] = e1;
        sj[j][4*a+2] = e2; sj[j][4*a+3] = e3;
        sum += (e0 + e1) + (e2 + e3);
      }
    sum += __shfl_xor(sum, 32);
    const float inv = 1.f / sum;
    unsigned P2[4][4][2];
    #pragma unroll
    for (int j = 0; j < 4; ++j)
      #pragma unroll
      for (int a = 0; a < 4; ++a) {
        P2[j][a][0] = cvtpk(sj[j][4*a+0], sj[j][4*a+1]);
        P2[j][a][1] = cvtpk(sj[j][4*a+2], sj[j][4*a+3]);
      }

    // ---- prefetch proj weights+bias (R13-verified): VMEM queue empty; PV loop
    // (lgkm ds_reads + shfl + MFMA) + epilogue + barrier cover the L2 latency.
    {
      const int ot = wid & 7;
      const unsigned short* wptr = wproj + (size_t)(ot*16 + c)*128;
      #pragma unroll
      for (int kk = 0; kk < 4; ++kk) pjw[kk] = *(const bf8*)(wptr + kk*32 + g*8);
      pjb = *(const f4*)(proj_b + ot*16 + g*4);
    }

    const f16v z16 = {0.f,0.f,0.f,0.f,0.f,0.f,0.f,0.f,0.f,0.f,0.f,0.f,0.f,0.f,0.f,0.f};
    f16v acc = z16;
    #pragma unroll
    for (int km = 0; km < 7; ++km) {
      const int j = km >> 1, a0 = 2*(km & 1);
      bf8 vf = *(const bf8*)&vt[(hh*32 + l31)*SROW + km*16 + hl*8];
      unsigned o0 = P2[j][a0][0],   o1 = P2[j][a0][1];
      unsigned o2 = P2[j][a0+1][0], o3 = P2[j][a0+1][1];
      unsigned s0 = __shfl_xor(o0, 32), s1 = __shfl_xor(o1, 32);
      unsigned s2 = __shfl_xor(o2, 32), s3 = __shfl_xor(o3, 32);
      u32x4 pw;
      pw[0] = hl ? s2 : o0;  pw[1] = hl ? s3 : o1;
      pw[2] = hl ? o2 : s0;  pw[3] = hl ? o3 : s1;
      acc = MFMA32(vf, *(bf8*)&pw, acc);   // out^T[d][n]
    }
    #pragma unroll
    for (int a = 0; a < 4; ++a) {
      u32x2 uu;
      uu[0] = cvtpk(acc[4*a+0]*inv, acc[4*a+1]*inv);
      uu[1] = cvtpk(acc[4*a+2]*inv, acc[4*a+3]*inv);
      *(u32x2*)&xb[nA*SROW + hh*32 + a*8 + hl*4] = uu;
    }
  }
  __syncthreads();

  // ---- proj: col-tile ownership; weights/bias already in registers ----
  {
    const int ot = wid & 7;
    const int ibase = (wid < 8) ? 0 : 4;
    const int nrows = (wid < 8) ? 4 : 3;
    #pragma unroll
    for (int i = 0; i < 4; ++i) if (i < nrows) {
      const int row = ibase + i;
      f4 acc = {0.f, 0.f, 0.f, 0.f};
      #pragma unroll
      for (int kk = 0; kk < 4; ++kk) {
        bf8 xf = *(const bf8*)(&xb[(row*16 + c)*SROW + kk*32 + g*8]);
        acc = MFMA16(pjw[kk], xf, acc);   // D[o'][n']
      }
      const int n2 = row*16 + c;
      if (n2 < NTOK) {
        f4 o4 = {acc[0]+pjb[0], acc[1]+pjb[1], acc[2]+pjb[2], acc[3]+pjb[3]};
        *(f4*)(out + (size_t)b*(NTOK*128) + n2*128 + ot*16 + g*4) = o4;
      }
    }
  }
}

extern "C" void kernel_launch(void* const* d_in, const int* in_sizes, int n_in,
                              void* d_out, int out_size, void* d_ws, size_t ws_size,
                              hipStream_t stream) {
  const float* x          = (const float*)d_in[0];
  const float* mask       = (const float*)d_in[1];
  const float* qkv_w      = (const float*)d_in[2];
  const float* proj_w     = (const float*)d_in[3];
  const float* proj_b     = (const float*)d_in[4];
  const float* bias_table = (const float*)d_in[5];
  const int*   rel_index  = (const int*)d_in[6];

  // ws: wqkv bf16 (98,304) | wproj bf16 (32,768) | bsmall f32 229,376 @131,072 |
  //     bmh fp16 7,340,032 B @360,448
  unsigned short* wq = (unsigned short*)d_ws;
  unsigned short* wp = wq + 384*128;
  float* bsmall = (float*)((char*)d_ws + 131072);
  unsigned short* bmh = (unsigned short*)((char*)d_ws + 360448);

  const size_t need = 360448u + (size_t)64*4*128*112*2;
  const int use_bm = (ws_size >= need) ? 1 : 0;

  prep_kernel<<<2048, 256, 0, stream>>>(qkv_w, proj_w, bias_table, rel_index, mask,
                                        wq, wp, bsmall, bmh, use_bm);
  if (use_bm)
    wattn_kernel<1><<<4096, 1024, 0, stream>>>(x, mask, proj_b, wq, wp, bsmall, bmh,
                                               (float*)d_out);
  else
    wattn_kernel<0><<<4096, 1024, 0, stream>>>(x, mask, proj_b, wq, wp, bsmall, bmh,
                                               (float*)d_out);
}

// Round 17
// 262.608 us; speedup vs baseline: 1.0270x; 1.0270x over previous
//
#include <hip/hip_runtime.h>

typedef __attribute__((ext_vector_type(8))) short bf8;
typedef __attribute__((ext_vector_type(4))) float f4;
typedef __attribute__((ext_vector_type(16))) float f16v;
typedef __attribute__((ext_vector_type(2))) unsigned int u32x2;
typedef __attribute__((ext_vector_type(4))) unsigned int u32x4;

#define MFMA16(A,B,C) __builtin_amdgcn_mfma_f32_16x16x32_bf16(A,B,C,0,0,0)
#define MFMA32(A,B,C) __builtin_amdgcn_mfma_f32_32x32x16_bf16(A,B,C,0,0,0)

#define NTOK 98
#define SROW 136
#define LOG2E 1.4426950408889634f
#define QSCALE (0.17677669529663687f * LOG2E)   // head scale * log2(e)

__device__ __forceinline__ unsigned short bfu(float f) {
  union { float f; unsigned u; } un; un.f = f;
  unsigned r = un.u + 0x7FFFu + ((un.u >> 16) & 1u);
  return (unsigned short)(r >> 16);
}
__device__ __forceinline__ unsigned cvtpk(float a, float b) {
  unsigned r;
  asm("v_cvt_pk_bf16_f32 %0, %1, %2" : "=v"(r) : "v"(a), "v"(b));
  return r;
}
__device__ __forceinline__ float h2f(unsigned short u) {
  return (float)__builtin_bit_cast(_Float16, u);
}

__global__ void prep_kernel(const float* __restrict__ qkv_w,
                            const float* __restrict__ proj_w,
                            const float* __restrict__ bias_table,
                            const int* __restrict__ rel_index,
                            const float* __restrict__ mask,
                            unsigned short* __restrict__ wq,
                            unsigned short* __restrict__ wp,
                            float* __restrict__ bsmall,
                            unsigned short* __restrict__ bmh, int use_bm) {
  const int T1 = 384*128, T2 = T1 + 128*128;
  const int TS = 4*128*112;
  const int T3 = T2 + TS;
  const int TB = 64*4*128*112;
  const int total = T3 + (use_bm ? TB : 0);
  for (int idx = blockIdx.x*blockDim.x + threadIdx.x; idx < total;
       idx += gridDim.x*blockDim.x) {
    if (idx < T1)      wq[idx] = bfu(qkv_w[idx]);
    else if (idx < T2) wp[idx - T1] = bfu(proj_w[idx - T1]);
    else if (idx < T3) {
      int t = idx - T2;
      int m = t % 112, n = (t/112) & 127, h = t / (112*128);
      float v;
      if (m >= NTOK)      v = -1e30f;
      else if (n >= NTOK) v = 0.f;
      else                v = bias_table[rel_index[n*98+m]*4 + h] * LOG2E;
      bsmall[t] = v;
    } else {
      int t = idx - T3;
      int m = t % 112; int r = t / 112;
      int n = r & 127; r >>= 7;
      int h = r & 3;   int w = r >> 2;
      float v;
      if (m >= NTOK)      v = -1e30f;   // fp16 -inf -> exp2 = 0
      else if (n >= NTOK) v = 0.f;
      else v = (bias_table[rel_index[n*98+m]*4 + h] + mask[(size_t)w*9604 + n*98 + m]) * LOG2E;
      bmh[t] = __builtin_bit_cast(unsigned short, (_Float16)v);
    }
  }
}

template<int USE_BM>
__launch_bounds__(1024, 1)
__global__ void wattn_kernel(const float* __restrict__ x,
                             const float* __restrict__ mask,
                             const float* __restrict__ proj_b,
                             const unsigned short* __restrict__ wqkv,
                             const unsigned short* __restrict__ wproj,
                             const float* __restrict__ bsmall,
                             const unsigned short* __restrict__ bmh,
                             float* __restrict__ out) {
  __shared__ unsigned short xb[128*SROW];   // x bf16, reused as attn-out [n][d]
  __shared__ unsigned short qb[128*SROW];   // q (QSCALE'd) [n][d]
  __shared__ unsigned short kb[128*SROW];   // k [m][d]
  __shared__ unsigned short vt[128*SROW];   // V^T [d][token]

  const int b = blockIdx.x, tid = threadIdx.x;
  const int wid = tid >> 6, lane = tid & 63;
  const int g = lane >> 4, c = lane & 15;
  const int hh = wid & 3, i32 = wid >> 2;
  const int l31 = lane & 31, hl = lane >> 5;
  const int nA = i32*32 + l31;

  // proj prefetch registers (loaded mid-attention, consumed after the barrier)
  bf8 pjw[4];
  f4  pjb;

  // ---- issue x loads early ----
  const float4* xp4 = (const float4*)(x + (size_t)b * (NTOK*128));
  float4 xv0 = xp4[tid];
  float4 xv1 = xp4[tid + 1024];
  float4 xv2 = xp4[tid + 2048];
  float4 xv3;
  const bool has3 = tid < 64;               // 3136 total float4
  if (has3) xv3 = xp4[tid + 3072];

  // zero pads: xb rows 98..111, qb/kb rows 112..127
  for (int i = tid; i < 14*SROW; i += 1024) xb[98*SROW + i] = 0;
  for (int i = tid; i < 16*SROW; i += 1024) { qb[112*SROW + i] = 0; kb[112*SROW + i] = 0; }

  // ---- convert + stage x ----
  {
    int e = tid*4, nn = e >> 7, cc = e & 127;
    u32x2 u; u[0] = cvtpk(xv0.x, xv0.y); u[1] = cvtpk(xv0.z, xv0.w);
    *(u32x2*)&xb[nn*SROW + cc] = u;
    e = (tid+1024)*4; nn = e >> 7; cc = e & 127;
    u[0] = cvtpk(xv1.x, xv1.y); u[1] = cvtpk(xv1.z, xv1.w);
    *(u32x2*)&xb[nn*SROW + cc] = u;
    e = (tid+2048)*4; nn = e >> 7; cc = e & 127;
    u[0] = cvtpk(xv2.x, xv2.y); u[1] = cvtpk(xv2.z, xv2.w);
    *(u32x2*)&xb[nn*SROW + cc] = u;
    if (has3) {
      e = (tid+3072)*4; nn = e >> 7; cc = e & 127;
      u[0] = cvtpk(xv3.x, xv3.y); u[1] = cvtpk(xv3.z, xv3.w);
      *(u32x2*)&xb[nn*SROW + cc] = u;
    }
  }
  __syncthreads();

  // ---- QKV: 48 half-tile tasks over 16 waves (R3/R8-verified, verbatim) ----
  for (int k3 = 0; k3 < 3; ++k3) {
    const int u = wid + 16*k3;
    const int ot = u >> 1, half = u & 1;
    const int ib = half ? 4 : 0, ni = half ? 3 : 4;
    if (ot < 16) {                      // q/k, operand-swapped
      const unsigned short* wptr = wqkv + (size_t)(ot*16 + c)*128;
      f4 acc[4] = {};
      #pragma unroll
      for (int kk = 0; kk < 4; ++kk) {
        bf8 wf = *(const bf8*)(wptr + kk*32 + g*8);
        #pragma unroll
        for (int i = 0; i < 4; ++i) if (i < ni) {
          bf8 xf = *(const bf8*)(&xb[((ib+i)*16 + c)*SROW + kk*32 + g*8]);
          acc[i] = MFMA16(wf, xf, acc[i]);   // D[o'][n']
        }
      }
      unsigned short* dst = (ot < 8) ? qb : kb;
      const int col = (ot & 7)*16 + g*4;
      const float sc = (ot < 8) ? QSCALE : 1.f;
      #pragma unroll
      for (int i = 0; i < 4; ++i) if (i < ni) {
        u32x2 uu;
        uu[0] = cvtpk(acc[i][0]*sc, acc[i][1]*sc);
        uu[1] = cvtpk(acc[i][2]*sc, acc[i][3]*sc);
        *(u32x2*)&dst[((ib+i)*16 + c)*SROW + col] = uu;
      }
    } else {                            // v -> V^T
      const int ov = ot - 16;
      const unsigned short* wptr = wqkv + (size_t)(256 + ov*16 + c)*128;
      f4 acc[4] = {};
      #pragma unroll
      for (int kk = 0; kk < 4; ++kk) {
        bf8 wf = *(const bf8*)(wptr + kk*32 + g*8);
        #pragma unroll
        for (int i = 0; i < 4; ++i) if (i < ni) {
          bf8 xf = *(const bf8*)(&xb[((ib+i)*16 + c)*SROW + kk*32 + g*8]);
          acc[i] = MFMA16(xf, wf, acc[i]);   // D[n'][o']
        }
      }
      #pragma unroll
      for (int i = 0; i < 4; ++i) if (i < ni) {
        u32x2 uu;
        uu[0] = cvtpk(acc[i][0], acc[i][1]);
        uu[1] = cvtpk(acc[i][2], acc[i][3]);
        *(u32x2*)&vt[(ov*16 + c)*SROW + (ib+i)*16 + g*4] = uu;
      }
    }
  }
  __syncthreads();

  // ---- attention: 1 task/wave; fp16 bm as MFMA C-init (loads at phase entry) ----
  {
    f16v sj[4];
    if (USE_BM) {
      const unsigned short* bp = bmh + ((size_t)((b & 63)*4 + hh)*128 + nA)*112;
      #pragma unroll
      for (int j = 0; j < 4; ++j)
        #pragma unroll
        for (int a = 0; a < 4; ++a) {
          if (j == 3 && a >= 2) {
            sj[j][4*a+0] = 0.f; sj[j][4*a+1] = 0.f;
            sj[j][4*a+2] = 0.f; sj[j][4*a+3] = 0.f;   // masked region: P=0 directly
          } else {
            ushort4 t = *(const ushort4*)(bp + j*32 + a*8 + hl*4);
            sj[j][4*a+0] = h2f(t.x); sj[j][4*a+1] = h2f(t.y);
            sj[j][4*a+2] = h2f(t.z); sj[j][4*a+3] = h2f(t.w);
          }
        }
    } else {
      const float* bs = bsmall + ((size_t)hh*128 + nA)*112;
      #pragma unroll
      for (int j = 0; j < 4; ++j)
        #pragma unroll
        for (int a = 0; a < 4; ++a) {
          if (j == 3 && a >= 2) {
            sj[j][4*a+0] = 0.f; sj[j][4*a+1] = 0.f;
            sj[j][4*a+2] = 0.f; sj[j][4*a+3] = 0.f;
          } else {
            f4 t = *(const f4*)(bs + j*32 + a*8 + hl*4);
            sj[j][4*a+0] = t[0]; sj[j][4*a+1] = t[1];
            sj[j][4*a+2] = t[2]; sj[j][4*a+3] = t[3];
          }
        }
    }
    if (!USE_BM && nA < NTOK) {
      const float* mw = mask + (size_t)(b & 63)*9604 + (size_t)nA*98;
      #pragma unroll
      for (int j = 0; j < 4; ++j)
        #pragma unroll
        for (int a = 0; a < 4; ++a) {
          if (j == 3 && a >= 2) continue;
          #pragma unroll
          for (int bb = 0; bb < 4; ++bb) {
            int m = j*32 + a*8 + hl*4 + bb;
            if (m < NTOK) sj[j][4*a+bb] += mw[m] * LOG2E;
          }
        }
    }
    // QK^T: S^T[m][n], col n = nA
    #pragma unroll
    for (int kd = 0; kd < 2; ++kd) {
      bf8 qf = *(const bf8*)&qb[nA*SROW + hh*32 + kd*16 + hl*8];
      #pragma unroll
      for (int j = 0; j < 4; ++j) {
        bf8 kf = *(const bf8*)&kb[(j*32 + l31)*SROW + hh*32 + kd*16 + hl*8];
        sj[j] = MFMA32(kf, qf, sj[j]);
      }
    }
    // softmax: exp2 (log2e pre-folded); skip 8 always-masked regs
    float sum = 0.f;
    #pragma unroll
    for (int j = 0; j < 4; ++j)
      #pragma unroll
      for (int a = 0; a < 4; ++a) {
        if (j == 3 && a >= 2) {
          sj[j][4*a+0] = 0.f; sj[j][4*a+1] = 0.f;
          sj[j][4*a+2] = 0.f; sj[j][4*a+3] = 0.f;
          continue;
        }
        float e0 = exp2f(sj[j][4*a+0]);
        float e1 = exp2f(sj[j][4*a+1]);
        float e2 = exp2f(sj[j][4*a+2]);
        float e3 = exp2f(sj[j][4*a+3]);
        sj[j][4*a+0] = e0; sj[j][4*a+1] = e1;
        sj[j][4*a+2] = e2; sj[j][4*a+3] = e3;
        sum += (e0 + e1) + (e2 + e3);
      }
    sum += __shfl_xor(sum, 32);
    const float inv = 1.f / sum;
    unsigned P2[4][4][2];
    #pragma unroll
    for (int j = 0; j < 4; ++j)
      #pragma unroll
      for (int a = 0; a < 4; ++a) {
        P2[j][a][0] = cvtpk(sj[j][4*a+0], sj[j][4*a+1]);
        P2[j][a][1] = cvtpk(sj[j][4*a+2], sj[j][4*a+3]);
      }

    // ---- prefetch proj weights+bias (R13-verified): VMEM queue empty; PV loop
    // (lgkm ds_reads + permlane + MFMA) + epilogue + barrier cover the L2 latency.
    {
      const int ot = wid & 7;
      const unsigned short* wptr = wproj + (size_t)(ot*16 + c)*128;
      #pragma unroll
      for (int kk = 0; kk < 4; ++kk) pjw[kk] = *(const bf8*)(wptr + kk*32 + g*8);
      pjb = *(const f4*)(proj_b + ot*16 + g*4);
    }

    const f16v z16 = {0.f,0.f,0.f,0.f,0.f,0.f,0.f,0.f,0.f,0.f,0.f,0.f,0.f,0.f,0.f,0.f};
    f16v acc = z16;
    #pragma unroll
    for (int km = 0; km < 7; ++km) {
      const int j = km >> 1, a0 = 2*(km & 1);
      bf8 vf = *(const bf8*)&vt[(hh*32 + l31)*SROW + km*16 + hl*8];
      // P redistribution via v_permlane32_swap_b32 (replaces 4 ds_bpermute +
      // 4 cndmask). After swap(A,B): A' = {A_lo, B_lo}, B' = {A_hi, B_hi}:
      //   A'[lane<32]=A[lane], A'[lane>=32]=B[lane-32]  == (hl ? sB : oA)
      //   B'[lane<32]=A[lane+32], B'[lane>=32]=B[lane]  == (hl ? oB : sA)
      unsigned A0 = P2[j][a0][0],   B0 = P2[j][a0+1][0];
      unsigned A1 = P2[j][a0][1],   B1 = P2[j][a0+1][1];
      asm("v_permlane32_swap_b32 %0, %1" : "+v"(A0), "+v"(B0));
      asm("v_permlane32_swap_b32 %0, %1" : "+v"(A1), "+v"(B1));
      u32x4 pw;
      pw[0] = A0;  pw[1] = A1;
      pw[2] = B0;  pw[3] = B1;
      acc = MFMA32(vf, *(bf8*)&pw, acc);   // out^T[d][n]
    }
    #pragma unroll
    for (int a = 0; a < 4; ++a) {
      u32x2 uu;
      uu[0] = cvtpk(acc[4*a+0]*inv, acc[4*a+1]*inv);
      uu[1] = cvtpk(acc[4*a+2]*inv, acc[4*a+3]*inv);
      *(u32x2*)&xb[nA*SROW + hh*32 + a*8 + hl*4] = uu;
    }
  }
  __syncthreads();

  // ---- proj: col-tile ownership; weights/bias already in registers ----
  {
    const int ot = wid & 7;
    const int ibase = (wid < 8) ? 0 : 4;
    const int nrows = (wid < 8) ? 4 : 3;
    #pragma unroll
    for (int i = 0; i < 4; ++i) if (i < nrows) {
      const int row = ibase + i;
      f4 acc = {0.f, 0.f, 0.f, 0.f};
      #pragma unroll
      for (int kk = 0; kk < 4; ++kk) {
        bf8 xf = *(const bf8*)(&xb[(row*16 + c)*SROW + kk*32 + g*8]);
        acc = MFMA16(pjw[kk], xf, acc);   // D[o'][n']
      }
      const int n2 = row*16 + c;
      if (n2 < NTOK) {
        f4 o4 = {acc[0]+pjb[0], acc[1]+pjb[1], acc[2]+pjb[2], acc[3]+pjb[3]};
        *(f4*)(out + (size_t)b*(NTOK*128) + n2*128 + ot*16 + g*4) = o4;
      }
    }
  }
}

extern "C" void kernel_launch(void* const* d_in, const int* in_sizes, int n_in,
                              void* d_out, int out_size, void* d_ws, size_t ws_size,
                              hipStream_t stream) {
  const float* x          = (const float*)d_in[0];
  const float* mask       = (const float*)d_in[1];
  const float* qkv_w      = (const float*)d_in[2];
  const float* proj_w     = (const float*)d_in[3];
  const float* proj_b     = (const float*)d_in[4];
  const float* bias_table = (const float*)d_in[5];
  const int*   rel_index  = (const int*)d_in[6];

  // ws: wqkv bf16 (98,304) | wproj bf16 (32,768) | bsmall f32 229,376 @131,072 |
  //     bmh fp16 7,340,032 B @360,448
  unsigned short* wq = (unsigned short*)d_ws;
  unsigned short* wp = wq + 384*128;
  float* bsmall = (float*)((char*)d_ws + 131072);
  unsigned short* bmh = (unsigned short*)((char*)d_ws + 360448);

  const size_t need = 360448u + (size_t)64*4*128*112*2;
  const int use_bm = (ws_size >= need) ? 1 : 0;

  prep_kernel<<<2048, 256, 0, stream>>>(qkv_w, proj_w, bias_table, rel_index, mask,
                                        wq, wp, bsmall, bmh, use_bm);
  if (use_bm)
    wattn_kernel<1><<<4096, 1024, 0, stream>>>(x, mask, proj_b, wq, wp, bsmall, bmh,
                                               (float*)d_out);
  else
    wattn_kernel<0><<<4096, 1024, 0, stream>>>(x, mask, proj_b, wq, wp, bsmall, bmh,
                                               (float*)d_out);
}